// Round 6
// baseline (92.085 us; speedup 1.0000x reference)
//
#include <hip/hip_runtime.h>
#include <hip/hip_bf16.h>

#define BB 1024
#define DD 256
#define NREL 42

typedef __attribute__((ext_vector_type(8))) short short8_t;
typedef __attribute__((ext_vector_type(4))) short short4_t;
typedef __attribute__((ext_vector_type(4))) float f32x4;
typedef __attribute__((ext_vector_type(4))) int   i32x4;

__device__ __forceinline__ unsigned short bf16_of(float f) {
    // round-to-nearest-even f32 -> bf16 (inputs are finite normals)
    unsigned u = __float_as_uint(f);
    return (unsigned short)((u + 0x7FFFu + ((u >> 16) & 1u)) >> 16);
}

// ---------------- K0: x -> bf16 row-major + LDS-tiled transpose -----------------
__global__ __launch_bounds__(256) void cvt_kernel(const float* __restrict__ x,
                                                  unsigned short* __restrict__ xbf,
                                                  unsigned short* __restrict__ xbfT) {
    __shared__ unsigned short t[64][72];
    const int bj = blockIdx.x * 64;
    const int bd = blockIdx.y * 64;
    const int tr = threadIdx.x >> 4;
    const int tc = threadIdx.x & 15;

    #pragma unroll
    for (int rr = 0; rr < 4; ++rr) {
        const int jl = rr * 16 + tr;
        const f32x4 v = *reinterpret_cast<const f32x4*>(&x[(bj + jl) * DD + bd + tc * 4]);
        short4_t h;
        #pragma unroll
        for (int e = 0; e < 4; ++e) h[e] = (short)bf16_of(v[e]);
        *reinterpret_cast<short4_t*>(&xbf[(bj + jl) * DD + bd + tc * 4]) = h;
        *reinterpret_cast<short4_t*>(&t[jl][tc * 4]) = h;
    }
    __syncthreads();
    #pragma unroll
    for (int rr = 0; rr < 4; ++rr) {
        const int dl = rr * 16 + tr;
        short4_t h;
        #pragma unroll
        for (int e = 0; e < 4; ++e) h[e] = (short)t[tc * 4 + e][dl];
        *reinterpret_cast<short4_t*>(&xbfT[(bd + dl) * BB + bj + tc * 4]) = h;
    }
}

// ---------------- K1 (fused): logits GEMM + gather + softmax -> normalized P ----
// 1024 blocks x 128 thr (2 waves). Block owns row i; wave w owns j-half w.
// A_i (48x256 bf16) in VGPRs. B (16-j subtiles of xbf) loaded global->register
// (xbf is L2-resident; no LDS staging, NO barriers in the K-loop) with explicit
// ping-pong prefetch. Epilogue selects S[q[i,j], j] into LDS; one barrier; both
// waves reduce the full row; each writes its P half (pre-normalized).
__global__ __launch_bounds__(128, 2) void attn_kernel(const float* __restrict__ x,
                                                      const int* __restrict__ q,
                                                      const float* __restrict__ R,
                                                      const unsigned short* __restrict__ xbf,
                                                      unsigned short* __restrict__ P) {
    __shared__ float s_attn[BB];           // 4 KB: logit row for this i
    __shared__ unsigned short s_qs[BB];    // 2 KB: q row (values < 42)

    const int tid  = threadIdx.x;
    const int w    = tid >> 6;       // 0/1: j-half
    const int lane = tid & 63;
    const int lcol = lane & 15;
    const int g    = lane >> 4;
    const int lk8  = g * 8;
    const int i    = blockIdx.x;

    // --- q row -> LDS (u16): 128 threads x 8 values ---
    {
        const int c8 = tid * 8;
        const i32x4 qa = *reinterpret_cast<const i32x4*>(&q[i * BB + c8]);
        const i32x4 qb = *reinterpret_cast<const i32x4*>(&q[i * BB + c8 + 4]);
        short4_t sa, sb;
        sa[0] = (short)qa[0]; sa[1] = (short)qa[1]; sa[2] = (short)qa[2]; sa[3] = (short)qa[3];
        sb[0] = (short)qb[0]; sb[1] = (short)qb[1]; sb[2] = (short)qb[2]; sb[3] = (short)qb[3];
        *reinterpret_cast<short4_t*>(&s_qs[c8])     = sa;
        *reinterpret_cast<short4_t*>(&s_qs[c8 + 4]) = sb;
    }

    // --- A_i fragments in registers: afrag[mt*8+ks] = bf16(R[k][d]*x[i][d]) ---
    short8_t afrag[24];
    #pragma unroll
    for (int ks = 0; ks < 8; ++ks) {
        const int d0 = ks * 32 + lk8;
        const f32x4 x0 = *reinterpret_cast<const f32x4*>(&x[i * DD + d0]);
        const f32x4 x1 = *reinterpret_cast<const f32x4*>(&x[i * DD + d0 + 4]);
        #pragma unroll
        for (int mt = 0; mt < 3; ++mt) {
            const int k = mt * 16 + lcol;
            short8_t v = (short8_t)0;
            if (k < NREL) {
                const f32x4 r0 = *reinterpret_cast<const f32x4*>(&R[k * DD + d0]);
                const f32x4 r1 = *reinterpret_cast<const f32x4*>(&R[k * DD + d0 + 4]);
                #pragma unroll
                for (int e = 0; e < 4; ++e) {
                    v[e]     = (short)bf16_of(r0[e] * x0[e]);
                    v[e + 4] = (short)bf16_of(r1[e] * x1[e]);
                }
            }
            afrag[mt * 8 + ks] = v;
        }
    }

    __syncthreads();   // s_qs ready (epilogue reads it)

    // Wave's B base: row (w*512 + lcol), col lk8; subtile s advances 16 rows.
    const unsigned short* bp = xbf + (size_t)(w * 512 + lcol) * DD + lk8;

    short8_t ba[8], bb[8];

    auto loadb = [&](short8_t (&b)[8], int s_) {
        const unsigned short* p = bp + (size_t)s_ * (16 * DD);
        #pragma unroll
        for (int k = 0; k < 8; ++k)
            b[k] = *reinterpret_cast<const short8_t*>(p + k * 32);
    };
    auto computeb = [&](short8_t (&b)[8], int s_) {
        f32x4 a0 = (f32x4)0.0f, a1 = (f32x4)0.0f, a2 = (f32x4)0.0f;
        #pragma unroll
        for (int ks = 0; ks < 8; ++ks) {
            a0 = __builtin_amdgcn_mfma_f32_16x16x32_bf16(afrag[ks],      b[ks], a0, 0, 0, 0);
            a1 = __builtin_amdgcn_mfma_f32_16x16x32_bf16(afrag[8 + ks],  b[ks], a1, 0, 0, 0);
            a2 = __builtin_amdgcn_mfma_f32_16x16x32_bf16(afrag[16 + ks], b[ks], a2, 0, 0, 0);
        }
        // Exactly one lane per j holds S[q[i,j], j]: row = g*4 + r = q&15, mt = q>>4.
        const int jl = w * 512 + s_ * 16 + lcol;
        const int qv = (int)s_qs[jl];
        if (((qv >> 2) & 3) == g) {
            const int mt = qv >> 4;
            const f32x4 av = (mt == 0) ? a0 : (mt == 1) ? a1 : a2;
            const float v = (qv & 2) ? ((qv & 1) ? av[3] : av[2])
                                     : ((qv & 1) ? av[1] : av[0]);
            s_attn[jl] = v;
        }
    };

    loadb(ba, 0);
    for (int s = 0; s < 32; s += 2) {
        loadb(bb, (s + 1 < 32) ? s + 1 : 31);   // prefetch next subtile
        computeb(ba, s);
        loadb(ba, (s + 2 < 32) ? s + 2 : 31);   // prefetch next-next
        computeb(bb, s + 1);
    }

    __syncthreads();   // s_attn complete

    // --- softmax: full-row reduce (redundant per wave), write own P half ---
    f32x4 v4[4];
    #pragma unroll
    for (int kk = 0; kk < 4; ++kk)
        v4[kk] = *reinterpret_cast<const f32x4*>(&s_attn[kk * 256 + lane * 4]);

    float m = -1e30f;
    #pragma unroll
    for (int kk = 0; kk < 4; ++kk)
        m = fmaxf(m, fmaxf(fmaxf(v4[kk][0], v4[kk][1]), fmaxf(v4[kk][2], v4[kk][3])));
    #pragma unroll
    for (int off = 1; off < 64; off <<= 1) m = fmaxf(m, __shfl_xor(m, off));

    float e[16];
    float ssum = 0.f;
    #pragma unroll
    for (int kk = 0; kk < 4; ++kk)
        #pragma unroll
        for (int ee = 0; ee < 4; ++ee) {
            const float t2 = __expf(v4[kk][ee] - m);
            e[kk * 4 + ee] = t2;
            ssum += t2;
        }
    #pragma unroll
    for (int off = 1; off < 64; off <<= 1) ssum += __shfl_xor(ssum, off);
    const float inv = 1.0f / ssum;

    #pragma unroll
    for (int kk2 = 0; kk2 < 2; ++kk2) {
        const int kk = w * 2 + kk2;
        short4_t p;
        #pragma unroll
        for (int ee = 0; ee < 4; ++ee) p[ee] = (short)bf16_of(e[kk * 4 + ee] * inv);
        *reinterpret_cast<short4_t*>(&P[i * BB + kk * 256 + lane * 4]) = p;
    }
}

// ---------------- K3a: partial out GEMM, split-K z=4 -----------------------------
__global__ __launch_bounds__(256) void out_partial(const unsigned short* __restrict__ P,
                                                   const unsigned short* __restrict__ xbfT,
                                                   float* __restrict__ part) {
    const int tid = threadIdx.x;
    const int wave = tid >> 6, lane = tid & 63;
    const int lcol = lane & 15;
    const int lk8  = (lane >> 4) * 8;
    const int i0 = blockIdx.y * 64 + wave * 16;
    const int d0 = blockIdx.x * 64;
    const int k0 = blockIdx.z * 256;

    f32x4 acc[4];
    #pragma unroll
    for (int nt = 0; nt < 4; ++nt) acc[nt] = (f32x4)0.0f;

    #pragma unroll
    for (int ks = 0; ks < 8; ++ks) {
        const short8_t a = *reinterpret_cast<const short8_t*>(
            &P[(i0 + lcol) * BB + k0 + ks * 32 + lk8]);
        #pragma unroll
        for (int nt = 0; nt < 4; ++nt) {
            const short8_t b = *reinterpret_cast<const short8_t*>(
                &xbfT[(d0 + nt * 16 + lcol) * BB + k0 + ks * 32 + lk8]);
            acc[nt] = __builtin_amdgcn_mfma_f32_16x16x32_bf16(a, b, acc[nt], 0, 0, 0);
        }
    }

    const int rbase = (lane >> 4) * 4;
    float* pz = part + (size_t)blockIdx.z * BB * DD;
    #pragma unroll
    for (int r = 0; r < 4; ++r)
        #pragma unroll
        for (int nt = 0; nt < 4; ++nt)
            pz[(i0 + rbase + r) * DD + d0 + nt * 16 + lcol] = acc[nt][r];
}

// ---------------- K3b: out = sum_z part[z] (P already normalized) ---------------
__global__ __launch_bounds__(256) void out_reduce(const float* __restrict__ part,
                                                  float* __restrict__ out) {
    const int idx = blockIdx.x * DD + threadIdx.x;
    out[idx] = (part[idx] + part[BB * DD + idx]) +
               (part[2 * BB * DD + idx] + part[3 * BB * DD + idx]);
}

// ---------------- launch ---------------------------------------------------------
extern "C" void kernel_launch(void* const* d_in, const int* in_sizes, int n_in,
                              void* d_out, int out_size, void* d_ws, size_t ws_size,
                              hipStream_t stream) {
    (void)in_sizes; (void)n_in; (void)out_size; (void)ws_size;
    const float* x = (const float*)d_in[0];
    // d_in[1] = x_mask (unused), d_in[3] = f (unused)
    const int* q = (const int*)d_in[2];
    const float* R = (const float*)d_in[4];
    float* out = (float*)d_out;

    char* ws = (char*)d_ws;
    unsigned short* xbf  = (unsigned short*)(ws);                  // 512 KB
    unsigned short* xbfT = (unsigned short*)(ws + (512u << 10));   // 512 KB
    unsigned short* P    = (unsigned short*)(ws + (1024u << 10));  // 2 MB
    float*          part = (float*)(ws + (3072u << 10));           // 4 MB (z=4)

    cvt_kernel<<<dim3(16, 4), 256, 0, stream>>>(x, xbf, xbfT);
    attn_kernel<<<dim3(BB), 128, 0, stream>>>(x, q, R, xbf, P);
    out_partial<<<dim3(4, 16, 4), 256, 0, stream>>>(P, xbfT, part);
    out_reduce<<<dim3(BB), 256, 0, stream>>>(part, out);
}

// Round 7
// 86.798 us; speedup vs baseline: 1.0609x; 1.0609x over previous
//
#include <hip/hip_runtime.h>
#include <hip/hip_bf16.h>

#define BB 1024
#define DD 256
#define NREL 42

typedef __attribute__((ext_vector_type(8))) short short8_t;
typedef __attribute__((ext_vector_type(4))) short short4_t;
typedef __attribute__((ext_vector_type(4))) float f32x4;
typedef __attribute__((ext_vector_type(4))) int   i32x4;

__device__ __forceinline__ unsigned short bf16_of(float f) {
    // round-to-nearest-even f32 -> bf16 (inputs are finite normals)
    unsigned u = __float_as_uint(f);
    return (unsigned short)((u + 0x7FFFu + ((u >> 16) & 1u)) >> 16);
}

__device__ __forceinline__ void gload_lds16(const unsigned short* g, unsigned short* l) {
    __builtin_amdgcn_global_load_lds(
        (const __attribute__((address_space(1))) unsigned int*)g,
        (__attribute__((address_space(3))) unsigned int*)l, 16, 0, 0);
}

// ---------------- K0: x -> bf16 row-major + LDS-tiled transpose -----------------
__global__ __launch_bounds__(256) void cvt_kernel(const float* __restrict__ x,
                                                  unsigned short* __restrict__ xbf,
                                                  unsigned short* __restrict__ xbfT) {
    __shared__ unsigned short t[64][72];
    const int bj = blockIdx.x * 64;
    const int bd = blockIdx.y * 64;
    const int tr = threadIdx.x >> 4;
    const int tc = threadIdx.x & 15;

    #pragma unroll
    for (int rr = 0; rr < 4; ++rr) {
        const int jl = rr * 16 + tr;
        const f32x4 v = *reinterpret_cast<const f32x4*>(&x[(bj + jl) * DD + bd + tc * 4]);
        short4_t h;
        #pragma unroll
        for (int e = 0; e < 4; ++e) h[e] = (short)bf16_of(v[e]);
        *reinterpret_cast<short4_t*>(&xbf[(bj + jl) * DD + bd + tc * 4]) = h;
        *reinterpret_cast<short4_t*>(&t[jl][tc * 4]) = h;
    }
    __syncthreads();
    #pragma unroll
    for (int rr = 0; rr < 4; ++rr) {
        const int dl = rr * 16 + tr;
        short4_t h;
        #pragma unroll
        for (int e = 0; e < 4; ++e) h[e] = (short)t[tc * 4 + e][dl];
        *reinterpret_cast<short4_t*>(&xbfT[(bd + dl) * BB + bj + tc * 4]) = h;
    }
}

// ---------------- K1 (fused): logits GEMM + gather + softmax -> normalized P ----
// 512 blocks x 256 thr (4 waves; 2 blocks/CU -> 2 waves/SIMD, independent).
// Block owns rows i0,i0+1; waves (2p, 2p+1) serve row i0+p, splitting each
// 32-j tile 16/16. A_i (48x256 bf16) in VGPRs. B tiles (32 j x 256 d,
// XOR-swizzled) TRIPLE-buffered in LDS via global_load_lds, 2 tiles prefetch
// depth, counted vmcnt(4) (never a full drain in steady state), ONE barrier
// per tile. Epilogue gathers S[q[i,j], j]; per-wave softmax writes P half.
__global__ __launch_bounds__(256, 2) void attn_kernel(const float* __restrict__ x,
                                                      const int* __restrict__ q,
                                                      const float* __restrict__ R,
                                                      const unsigned short* __restrict__ xbf,
                                                      unsigned short* __restrict__ P) {
    __shared__ unsigned short Bt[3][8192];      // 3 x (32 j x 256 d) bf16, swizzled
    __shared__ float s_attn[2][BB];             // per-i logit row
    __shared__ unsigned short s_qs[2][BB];      // per-i q row (values < 42)

    const int tid  = threadIdx.x;
    const int w    = tid >> 6;       // 0..3
    const int lane = tid & 63;
    const int p    = w >> 1;         // 0/1: which i this wave serves
    const int jh   = w & 1;          // 0/1: which 16-j half of the tile
    const int lcol = lane & 15;
    const int g    = lane >> 4;
    const int lk8  = g * 8;
    const int l5   = lane >> 5, l31 = lane & 31;
    const int i    = blockIdx.x * 2 + p;

    // --- q rows -> LDS (u16): 2 rows x 1024 over 256 threads, 8 each ---
    {
        const int r  = tid >> 7;
        const int c8 = (tid & 127) * 8;
        const int qi = blockIdx.x * 2 + r;
        const i32x4 qa = *reinterpret_cast<const i32x4*>(&q[qi * BB + c8]);
        const i32x4 qb = *reinterpret_cast<const i32x4*>(&q[qi * BB + c8 + 4]);
        short4_t sa, sb;
        sa[0] = (short)qa[0]; sa[1] = (short)qa[1]; sa[2] = (short)qa[2]; sa[3] = (short)qa[3];
        sb[0] = (short)qb[0]; sb[1] = (short)qb[1]; sb[2] = (short)qb[2]; sb[3] = (short)qb[3];
        *reinterpret_cast<short4_t*>(&s_qs[r][c8])     = sa;
        *reinterpret_cast<short4_t*>(&s_qs[r][c8 + 4]) = sb;
    }

    // --- A_i fragments in registers (issued BEFORE staging so the compiler's
    //     waits for these loads never drain the staging pipeline) ---
    short8_t afrag[24];
    #pragma unroll
    for (int ks = 0; ks < 8; ++ks) {
        const int d0 = ks * 32 + lk8;
        const f32x4 x0 = *reinterpret_cast<const f32x4*>(&x[i * DD + d0]);
        const f32x4 x1 = *reinterpret_cast<const f32x4*>(&x[i * DD + d0 + 4]);
        #pragma unroll
        for (int mt = 0; mt < 3; ++mt) {
            const int k = mt * 16 + lcol;
            short8_t v = (short8_t)0;
            if (k < NREL) {
                const f32x4 r0 = *reinterpret_cast<const f32x4*>(&R[k * DD + d0]);
                const f32x4 r1 = *reinterpret_cast<const f32x4*>(&R[k * DD + d0 + 4]);
                #pragma unroll
                for (int e = 0; e < 4; ++e) {
                    v[e]     = (short)bf16_of(r0[e] * x0[e]);
                    v[e + 4] = (short)bf16_of(r1[e] * x1[e]);
                }
            }
            afrag[mt * 8 + ks] = v;
        }
    }

    // --- stage tiles 0 and 1 (wave stages 4 chunks each; chunk = 2 rows x 512B) ---
    #pragma unroll
    for (int b = 0; b < 2; ++b) {
        const unsigned short* src = &xbf[b * 32 * DD];
        #pragma unroll
        for (int c0 = 0; c0 < 4; ++c0) {
            const int c = w * 4 + c0;
            const int row = c * 2 + l5;
            const int scol = ((l31 * 16) ^ ((row & 7) << 4)) >> 1;   // pre-swizzled src
            gload_lds16(&src[row * DD + scol], &Bt[b][c * 512]);
        }
    }

    asm volatile("s_waitcnt vmcnt(4)" ::: "memory");   // tile 0 done; tile 1 in flight
    __syncthreads();

    const int gsw  = (g * 16) ^ ((lcol & 7) << 4);   // swizzled in-row byte base
    const int brow = jh * 16 + lcol;                 // my B row within the tile

    int cs = 0, st = 2;   // compute buffer, stage buffer ((t+2)%3)
    for (int t = 0; t < 32; ++t) {
        // stage tile t+2 (2-deep prefetch; latency spans this whole iteration)
        if (t < 30) {
            unsigned short* nxt = Bt[st];
            const unsigned short* src = &xbf[(t + 2) * 32 * DD];
            #pragma unroll
            for (int c0 = 0; c0 < 4; ++c0) {
                const int c = w * 4 + c0;
                const int row = c * 2 + l5;
                const int scol = ((l31 * 16) ^ ((row & 7) << 4)) >> 1;
                gload_lds16(&src[row * DD + scol], &nxt[c * 512]);
            }
        }

        const char* cur = (const char*)Bt[cs];
        f32x4 a0 = (f32x4)0.0f, a1 = (f32x4)0.0f, a2 = (f32x4)0.0f;

        #pragma unroll
        for (int ks = 0; ks < 8; ++ks) {
            const int off = brow * 512 + ((ks * 64) ^ gsw);
            const short8_t b = *reinterpret_cast<const short8_t*>(cur + off);
            a0 = __builtin_amdgcn_mfma_f32_16x16x32_bf16(afrag[ks],      b, a0, 0, 0, 0);
            a1 = __builtin_amdgcn_mfma_f32_16x16x32_bf16(afrag[8 + ks],  b, a1, 0, 0, 0);
            a2 = __builtin_amdgcn_mfma_f32_16x16x32_bf16(afrag[16 + ks], b, a2, 0, 0, 0);
        }

        // Epilogue: my 16 j's; exactly one lane per j holds S[q[i,j], j].
        {
            const int jl = t * 32 + jh * 16 + lcol;
            const int qv = (int)s_qs[p][jl];
            if (((qv >> 2) & 3) == g) {
                const int mt = qv >> 4;                       // 0..2 (qv < 42)
                const f32x4 av = (mt == 0) ? a0 : (mt == 1) ? a1 : a2;
                const float v = (qv & 2) ? ((qv & 1) ? av[3] : av[2])
                                         : ((qv & 1) ? av[1] : av[0]);
                s_attn[p][jl] = v;
            }
        }

        // counted wait: tile t+1 done, tile t+2 stays in flight (tail drains)
        if (t < 30) asm volatile("s_waitcnt vmcnt(4)" ::: "memory");
        else        asm volatile("s_waitcnt vmcnt(0)" ::: "memory");
        __syncthreads();

        cs = (cs == 2) ? 0 : cs + 1;
        st = (st == 2) ? 0 : st + 1;
    }

    // --- softmax: full-row reduce (redundant in wave pair), write own P half ---
    f32x4 v4[4];
    #pragma unroll
    for (int kk = 0; kk < 4; ++kk)
        v4[kk] = *reinterpret_cast<const f32x4*>(&s_attn[p][kk * 256 + lane * 4]);

    float m = -1e30f;
    #pragma unroll
    for (int kk = 0; kk < 4; ++kk)
        m = fmaxf(m, fmaxf(fmaxf(v4[kk][0], v4[kk][1]), fmaxf(v4[kk][2], v4[kk][3])));
    #pragma unroll
    for (int off = 1; off < 64; off <<= 1) m = fmaxf(m, __shfl_xor(m, off));

    float e[16];
    float ssum = 0.f;
    #pragma unroll
    for (int kk = 0; kk < 4; ++kk)
        #pragma unroll
        for (int ee = 0; ee < 4; ++ee) {
            const float t2 = __expf(v4[kk][ee] - m);
            e[kk * 4 + ee] = t2;
            ssum += t2;
        }
    #pragma unroll
    for (int off = 1; off < 64; off <<= 1) ssum += __shfl_xor(ssum, off);
    const float inv = 1.0f / ssum;

    #pragma unroll
    for (int kk2 = 0; kk2 < 2; ++kk2) {
        const int kk = jh * 2 + kk2;
        short4_t pv;
        #pragma unroll
        for (int ee = 0; ee < 4; ++ee) pv[ee] = (short)bf16_of(e[kk * 4 + ee] * inv);
        *reinterpret_cast<short4_t*>(&P[i * BB + kk * 256 + lane * 4]) = pv;
    }
}

// ---------------- K3a: partial out GEMM, split-K z=4 -----------------------------
__global__ __launch_bounds__(256) void out_partial(const unsigned short* __restrict__ P,
                                                   const unsigned short* __restrict__ xbfT,
                                                   float* __restrict__ part) {
    const int tid = threadIdx.x;
    const int wave = tid >> 6, lane = tid & 63;
    const int lcol = lane & 15;
    const int lk8  = (lane >> 4) * 8;
    const int i0 = blockIdx.y * 64 + wave * 16;
    const int d0 = blockIdx.x * 64;
    const int k0 = blockIdx.z * 256;

    f32x4 acc[4];
    #pragma unroll
    for (int nt = 0; nt < 4; ++nt) acc[nt] = (f32x4)0.0f;

    #pragma unroll
    for (int ks = 0; ks < 8; ++ks) {
        const short8_t a = *reinterpret_cast<const short8_t*>(
            &P[(i0 + lcol) * BB + k0 + ks * 32 + lk8]);
        #pragma unroll
        for (int nt = 0; nt < 4; ++nt) {
            const short8_t b = *reinterpret_cast<const short8_t*>(
                &xbfT[(d0 + nt * 16 + lcol) * BB + k0 + ks * 32 + lk8]);
            acc[nt] = __builtin_amdgcn_mfma_f32_16x16x32_bf16(a, b, acc[nt], 0, 0, 0);
        }
    }

    const int rbase = (lane >> 4) * 4;
    float* pz = part + (size_t)blockIdx.z * BB * DD;
    #pragma unroll
    for (int r = 0; r < 4; ++r)
        #pragma unroll
        for (int nt = 0; nt < 4; ++nt)
            pz[(i0 + rbase + r) * DD + d0 + nt * 16 + lcol] = acc[nt][r];
}

// ---------------- K3b: out = sum_z part[z] (P already normalized) ---------------
__global__ __launch_bounds__(256) void out_reduce(const float* __restrict__ part,
                                                  float* __restrict__ out) {
    const int idx = blockIdx.x * DD + threadIdx.x;
    out[idx] = (part[idx] + part[BB * DD + idx]) +
               (part[2 * BB * DD + idx] + part[3 * BB * DD + idx]);
}

// ---------------- launch ---------------------------------------------------------
extern "C" void kernel_launch(void* const* d_in, const int* in_sizes, int n_in,
                              void* d_out, int out_size, void* d_ws, size_t ws_size,
                              hipStream_t stream) {
    (void)in_sizes; (void)n_in; (void)out_size; (void)ws_size;
    const float* x = (const float*)d_in[0];
    // d_in[1] = x_mask (unused), d_in[3] = f (unused)
    const int* q = (const int*)d_in[2];
    const float* R = (const float*)d_in[4];
    float* out = (float*)d_out;

    char* ws = (char*)d_ws;
    unsigned short* xbf  = (unsigned short*)(ws);                  // 512 KB
    unsigned short* xbfT = (unsigned short*)(ws + (512u << 10));   // 512 KB
    unsigned short* P    = (unsigned short*)(ws + (1024u << 10));  // 2 MB
    float*          part = (float*)(ws + (3072u << 10));           // 4 MB (z=4)

    cvt_kernel<<<dim3(16, 4), 256, 0, stream>>>(x, xbf, xbfT);
    attn_kernel<<<dim3(512), 256, 0, stream>>>(x, q, R, xbf, P);
    out_partial<<<dim3(4, 16, 4), 256, 0, stream>>>(P, xbfT, part);
    out_reduce<<<dim3(BB), 256, 0, stream>>>(part, out);
}

// Round 8
// 61.366 us; speedup vs baseline: 1.5006x; 1.4144x over previous
//
#include <hip/hip_runtime.h>
#include <hip/hip_bf16.h>

#define BB 1024
#define DD 256
#define NREL 42

typedef __attribute__((ext_vector_type(8))) short short8_t;
typedef __attribute__((ext_vector_type(4))) short short4_t;
typedef __attribute__((ext_vector_type(4))) float f32x4;
typedef __attribute__((ext_vector_type(4))) int   i32x4;

__device__ __forceinline__ unsigned short bf16_of(float f) {
    // round-to-nearest-even f32 -> bf16 (inputs are finite normals)
    unsigned u = __float_as_uint(f);
    return (unsigned short)((u + 0x7FFFu + ((u >> 16) & 1u)) >> 16);
}

__device__ __forceinline__ void gload_lds16(const unsigned short* g, unsigned short* l) {
    __builtin_amdgcn_global_load_lds(
        (const __attribute__((address_space(1))) unsigned int*)g,
        (__attribute__((address_space(3))) unsigned int*)l, 16, 0, 0);
}

// ---------------- K0: x -> bf16 row-major + LDS-tiled transpose -----------------
__global__ __launch_bounds__(256) void cvt_kernel(const float* __restrict__ x,
                                                  unsigned short* __restrict__ xbf,
                                                  unsigned short* __restrict__ xbfT) {
    __shared__ unsigned short t[64][72];
    const int bj = blockIdx.x * 64;
    const int bd = blockIdx.y * 64;
    const int tr = threadIdx.x >> 4;
    const int tc = threadIdx.x & 15;

    #pragma unroll
    for (int rr = 0; rr < 4; ++rr) {
        const int jl = rr * 16 + tr;
        const f32x4 v = *reinterpret_cast<const f32x4*>(&x[(bj + jl) * DD + bd + tc * 4]);
        short4_t h;
        #pragma unroll
        for (int e = 0; e < 4; ++e) h[e] = (short)bf16_of(v[e]);
        *reinterpret_cast<short4_t*>(&xbf[(bj + jl) * DD + bd + tc * 4]) = h;
        *reinterpret_cast<short4_t*>(&t[jl][tc * 4]) = h;
    }
    __syncthreads();
    #pragma unroll
    for (int rr = 0; rr < 4; ++rr) {
        const int dl = rr * 16 + tr;
        short4_t h;
        #pragma unroll
        for (int e = 0; e < 4; ++e) h[e] = (short)t[tc * 4 + e][dl];
        *reinterpret_cast<short4_t*>(&xbfT[(bd + dl) * BB + bj + tc * 4]) = h;
    }
}

// ---------------- K1 (fused): logits GEMM + gather + softmax -> normalized P ----
// 256 blocks x 256 thr (4 waves, 1 block/CU). Wave w owns row i = 4*blk + w:
// A_i (48x256 bf16) in VGPRs; per 64-j tile computes all 48x64 (96 MFMA, 12 acc
// chains). B tiles (64 j x 256 d, XOR-swizzled) TRIPLE-buffered in LDS via
// global_load_lds; 2-tile prefetch depth, counted vmcnt(8) (no full drain in
// steady state), ONE barrier per tile, 16 tiles total. Epilogue gathers
// S[q[i,j], j]; per-wave softmax normalizes and writes P.
__global__ __launch_bounds__(256, 1) void attn_kernel(const float* __restrict__ x,
                                                      const int* __restrict__ q,
                                                      const float* __restrict__ R,
                                                      const unsigned short* __restrict__ xbf,
                                                      unsigned short* __restrict__ P) {
    __shared__ unsigned short Bt[3][32768 / 2];  // 3 x (64 j x 256 d) bf16, swizzled
    __shared__ float s_attn[4][BB];              // per-wave logit row (16 KB)
    __shared__ unsigned short s_qs[4][BB];       // per-wave q row (8 KB)

    const int tid  = threadIdx.x;
    const int w    = tid >> 6;       // 0..3
    const int lane = tid & 63;
    const int lcol = lane & 15;
    const int g    = lane >> 4;
    const int lk8  = g * 8;
    const int l5   = lane >> 5, l31 = lane & 31;
    const int i    = blockIdx.x * 4 + w;

    // --- q row -> LDS (u16): wave loads its own row, 16 per lane ---
    #pragma unroll
    for (int kk = 0; kk < 4; ++kk) {
        const i32x4 qv = *reinterpret_cast<const i32x4*>(&q[i * BB + kk * 256 + lane * 4]);
        short4_t qs;
        qs[0] = (short)qv[0]; qs[1] = (short)qv[1];
        qs[2] = (short)qv[2]; qs[3] = (short)qv[3];
        *reinterpret_cast<short4_t*>(&s_qs[w][kk * 256 + lane * 4]) = qs;
    }

    // --- A_i fragments in registers: afrag[mt*8+ks] = bf16(R[k][d]*x[i][d]) ---
    short8_t afrag[24];
    #pragma unroll
    for (int ks = 0; ks < 8; ++ks) {
        const int d0 = ks * 32 + lk8;
        const f32x4 x0 = *reinterpret_cast<const f32x4*>(&x[i * DD + d0]);
        const f32x4 x1 = *reinterpret_cast<const f32x4*>(&x[i * DD + d0 + 4]);
        #pragma unroll
        for (int mt = 0; mt < 3; ++mt) {
            const int k = mt * 16 + lcol;
            short8_t v = (short8_t)0;
            if (k < NREL) {
                const f32x4 r0 = *reinterpret_cast<const f32x4*>(&R[k * DD + d0]);
                const f32x4 r1 = *reinterpret_cast<const f32x4*>(&R[k * DD + d0 + 4]);
                #pragma unroll
                for (int e = 0; e < 4; ++e) {
                    v[e]     = (short)bf16_of(r0[e] * x0[e]);
                    v[e + 4] = (short)bf16_of(r1[e] * x1[e]);
                }
            }
            afrag[mt * 8 + ks] = v;
        }
    }

    // --- stage tiles 0,1 (tile = 64 rows x 512 B = 32 chunks of 1 KB; wave: 8) ---
    #pragma unroll
    for (int b = 0; b < 2; ++b) {
        const unsigned short* src = &xbf[b * 64 * DD];
        #pragma unroll
        for (int c0 = 0; c0 < 8; ++c0) {
            const int c = w * 8 + c0;
            const int row = c * 2 + l5;
            const int scol = ((l31 * 16) ^ ((row & 7) << 4)) >> 1;   // pre-swizzled src
            gload_lds16(&src[row * DD + scol], &Bt[b][c * 512]);
        }
    }

    asm volatile("s_waitcnt vmcnt(8)" ::: "memory");   // tile 0 done; tile 1 in flight
    __syncthreads();

    const int gsw = (g * 16) ^ ((lcol & 7) << 4);   // swizzled in-row byte base

    int cs = 0, st = 2;   // compute buffer, stage buffer ((t+2)%3)
    for (int t = 0; t < 16; ++t) {
        // stage tile t+2 (2-deep prefetch; latency spans a full iteration)
        if (t < 14) {
            unsigned short* nxt = Bt[st];
            const unsigned short* src = &xbf[(t + 2) * 64 * DD];
            #pragma unroll
            for (int c0 = 0; c0 < 8; ++c0) {
                const int c = w * 8 + c0;
                const int row = c * 2 + l5;
                const int scol = ((l31 * 16) ^ ((row & 7) << 4)) >> 1;
                gload_lds16(&src[row * DD + scol], &nxt[c * 512]);
            }
        }

        const char* cur = (const char*)Bt[cs];
        f32x4 acc[3][4];
        #pragma unroll
        for (int mt = 0; mt < 3; ++mt)
            #pragma unroll
            for (int nt = 0; nt < 4; ++nt)
                acc[mt][nt] = (f32x4)0.0f;

        #pragma unroll
        for (int ks = 0; ks < 8; ++ks) {
            #pragma unroll
            for (int nt = 0; nt < 4; ++nt) {
                const int off = (nt * 16 + lcol) * 512 + ((ks * 64) ^ gsw);
                const short8_t b = *reinterpret_cast<const short8_t*>(cur + off);
                #pragma unroll
                for (int mt = 0; mt < 3; ++mt)
                    acc[mt][nt] = __builtin_amdgcn_mfma_f32_16x16x32_bf16(
                        afrag[mt * 8 + ks], b, acc[mt][nt], 0, 0, 0);
            }
        }

        // Epilogue: 64 j's; exactly one lane per j holds S[q[i,j], j].
        #pragma unroll
        for (int nt = 0; nt < 4; ++nt) {
            const int jl = t * 64 + nt * 16 + lcol;
            const int qv = (int)s_qs[w][jl];
            if (((qv >> 2) & 3) == g) {
                const int mt = qv >> 4;                       // 0..2 (qv < 42)
                const f32x4 av = (mt == 0) ? acc[0][nt] : (mt == 1) ? acc[1][nt] : acc[2][nt];
                const float v = (qv & 2) ? ((qv & 1) ? av[3] : av[2])
                                         : ((qv & 1) ? av[1] : av[0]);
                s_attn[w][jl] = v;
            }
        }

        // counted wait: tile t+1 complete, tile t+2 stays in flight
        if (t < 14) asm volatile("s_waitcnt vmcnt(8)" ::: "memory");
        else        asm volatile("s_waitcnt vmcnt(0)" ::: "memory");
        __syncthreads();

        cs = (cs == 2) ? 0 : cs + 1;
        st = (st == 2) ? 0 : st + 1;
    }

    // --- per-wave softmax over own row; write normalized P (bf16) ---
    f32x4 v4[4];
    #pragma unroll
    for (int kk = 0; kk < 4; ++kk)
        v4[kk] = *reinterpret_cast<const f32x4*>(&s_attn[w][kk * 256 + lane * 4]);

    float m = -1e30f;
    #pragma unroll
    for (int kk = 0; kk < 4; ++kk)
        m = fmaxf(m, fmaxf(fmaxf(v4[kk][0], v4[kk][1]), fmaxf(v4[kk][2], v4[kk][3])));
    #pragma unroll
    for (int off = 1; off < 64; off <<= 1) m = fmaxf(m, __shfl_xor(m, off));

    float e[16];
    float ssum = 0.f;
    #pragma unroll
    for (int kk = 0; kk < 4; ++kk)
        #pragma unroll
        for (int ee = 0; ee < 4; ++ee) {
            const float t2 = __expf(v4[kk][ee] - m);
            e[kk * 4 + ee] = t2;
            ssum += t2;
        }
    #pragma unroll
    for (int off = 1; off < 64; off <<= 1) ssum += __shfl_xor(ssum, off);
    const float inv = 1.0f / ssum;

    #pragma unroll
    for (int kk = 0; kk < 4; ++kk) {
        short4_t p;
        #pragma unroll
        for (int ee = 0; ee < 4; ++ee) p[ee] = (short)bf16_of(e[kk * 4 + ee] * inv);
        *reinterpret_cast<short4_t*>(&P[i * BB + kk * 256 + lane * 4]) = p;
    }
}

// ---------------- K3a: partial out GEMM, split-K z=4 -----------------------------
__global__ __launch_bounds__(256) void out_partial(const unsigned short* __restrict__ P,
                                                   const unsigned short* __restrict__ xbfT,
                                                   float* __restrict__ part) {
    const int tid = threadIdx.x;
    const int wave = tid >> 6, lane = tid & 63;
    const int lcol = lane & 15;
    const int lk8  = (lane >> 4) * 8;
    const int i0 = blockIdx.y * 64 + wave * 16;
    const int d0 = blockIdx.x * 64;
    const int k0 = blockIdx.z * 256;

    f32x4 acc[4];
    #pragma unroll
    for (int nt = 0; nt < 4; ++nt) acc[nt] = (f32x4)0.0f;

    #pragma unroll
    for (int ks = 0; ks < 8; ++ks) {
        const short8_t a = *reinterpret_cast<const short8_t*>(
            &P[(i0 + lcol) * BB + k0 + ks * 32 + lk8]);
        #pragma unroll
        for (int nt = 0; nt < 4; ++nt) {
            const short8_t b = *reinterpret_cast<const short8_t*>(
                &xbfT[(d0 + nt * 16 + lcol) * BB + k0 + ks * 32 + lk8]);
            acc[nt] = __builtin_amdgcn_mfma_f32_16x16x32_bf16(a, b, acc[nt], 0, 0, 0);
        }
    }

    const int rbase = (lane >> 4) * 4;
    float* pz = part + (size_t)blockIdx.z * BB * DD;
    #pragma unroll
    for (int r = 0; r < 4; ++r)
        #pragma unroll
        for (int nt = 0; nt < 4; ++nt)
            pz[(i0 + rbase + r) * DD + d0 + nt * 16 + lcol] = acc[nt][r];
}

// ---------------- K3b: out = sum_z part[z] (P already normalized) ---------------
__global__ __launch_bounds__(256) void out_reduce(const float* __restrict__ part,
                                                  float* __restrict__ out) {
    const int idx = blockIdx.x * DD + threadIdx.x;
    out[idx] = (part[idx] + part[BB * DD + idx]) +
               (part[2 * BB * DD + idx] + part[3 * BB * DD + idx]);
}

// ---------------- launch ---------------------------------------------------------
extern "C" void kernel_launch(void* const* d_in, const int* in_sizes, int n_in,
                              void* d_out, int out_size, void* d_ws, size_t ws_size,
                              hipStream_t stream) {
    (void)in_sizes; (void)n_in; (void)out_size; (void)ws_size;
    const float* x = (const float*)d_in[0];
    // d_in[1] = x_mask (unused), d_in[3] = f (unused)
    const int* q = (const int*)d_in[2];
    const float* R = (const float*)d_in[4];
    float* out = (float*)d_out;

    char* ws = (char*)d_ws;
    unsigned short* xbf  = (unsigned short*)(ws);                  // 512 KB
    unsigned short* xbfT = (unsigned short*)(ws + (512u << 10));   // 512 KB
    unsigned short* P    = (unsigned short*)(ws + (1024u << 10));  // 2 MB
    float*          part = (float*)(ws + (3072u << 10));           // 4 MB (z=4)

    cvt_kernel<<<dim3(16, 4), 256, 0, stream>>>(x, xbf, xbfT);
    attn_kernel<<<dim3(256), 256, 0, stream>>>(x, q, R, xbf, P);
    out_partial<<<dim3(4, 16, 4), 256, 0, stream>>>(P, xbfT, part);
    out_reduce<<<dim3(BB), 256, 0, stream>>>(part, out);
}

// Round 9
// 52.466 us; speedup vs baseline: 1.7551x; 1.1696x over previous
//
#include <hip/hip_runtime.h>
#include <hip/hip_bf16.h>

#define BB 1024
#define DD 256
#define NREL 42

typedef __attribute__((ext_vector_type(8))) short short8_t;
typedef __attribute__((ext_vector_type(4))) short short4_t;
typedef __attribute__((ext_vector_type(4))) float f32x4;
typedef __attribute__((ext_vector_type(4))) int   i32x4;

__device__ __forceinline__ unsigned short bf16_of(float f) {
    // round-to-nearest-even f32 -> bf16 (inputs are finite normals)
    unsigned u = __float_as_uint(f);
    return (unsigned short)((u + 0x7FFFu + ((u >> 16) & 1u)) >> 16);
}

// ---------------- K0: x -> bf16: fragment-major xfrag + transposed xbfT ----------
// xfrag layout: for 16-row j-group jg and K-step ks, lane l (l=0..63) holds
// bf16 x[jg*16 + (l&15)][ks*32 + (l>>4)*8 .. +8]  (the exact MFMA B fragment).
// Flat index: ((jg*8 + ks)*64 + l)*8 shorts. A wave's B-fragment load is then
// ONE fully-coalesced 1 KB global_load_dwordx4.
__global__ __launch_bounds__(256) void cvt_kernel(const float* __restrict__ x,
                                                  unsigned short* __restrict__ xfrag,
                                                  unsigned short* __restrict__ xbfT) {
    __shared__ unsigned short t[64][72];
    const int bj = blockIdx.x * 64;
    const int bd = blockIdx.y * 64;
    const int tid = threadIdx.x;
    const int tr = tid >> 4;
    const int tc = tid & 15;

    #pragma unroll
    for (int rr = 0; rr < 4; ++rr) {
        const int jl = rr * 16 + tr;
        const f32x4 v = *reinterpret_cast<const f32x4*>(&x[(bj + jl) * DD + bd + tc * 4]);
        short4_t h;
        #pragma unroll
        for (int e = 0; e < 4; ++e) h[e] = (short)bf16_of(v[e]);
        *reinterpret_cast<short4_t*>(&t[jl][tc * 4]) = h;
    }
    __syncthreads();

    // fragment-major writes: 64 rows x 8 d8-chunks = 512 chunks over 256 threads
    #pragma unroll
    for (int c = 0; c < 2; ++c) {
        const int idx = c * 256 + tid;
        const int jl  = idx & 63;          // row within tile (fastest -> coalesced)
        const int d8  = (idx >> 6) * 8;    // d-chunk within tile
        const int j   = bj + jl, d = bd + d8;
        const int jg = j >> 4, lc = j & 15, ks = d >> 5, g2 = (d >> 3) & 3;
        const short8_t v = *reinterpret_cast<const short8_t*>(&t[jl][d8]);
        *reinterpret_cast<short8_t*>(
            &xfrag[(size_t)(((jg * 8 + ks) * 64) + g2 * 16 + lc) * 8]) = v;
    }

    // transposed copy for the output GEMM
    #pragma unroll
    for (int rr = 0; rr < 4; ++rr) {
        const int dl = rr * 16 + tr;
        short4_t h;
        #pragma unroll
        for (int e = 0; e < 4; ++e) h[e] = (short)t[tc * 4 + e][dl];
        *reinterpret_cast<short4_t*>(&xbfT[(bd + dl) * BB + bj + tc * 4]) = h;
    }
}

// ---------------- K1 (fused): logits GEMM + gather + softmax -> normalized P ----
// 512 blocks x 256 thr (4 waves; ~2 blocks/CU -> 2 waves/SIMD, independent).
// Wave w: p=w&1 selects row i=blk*2+p, jh=w>>1 selects j-half. Wave pairs with
// the same jh (different i) share the identical B-load stream -> L1 hits.
// A_i (48x256 bf16) in VGPRs. B fragments loaded DIRECTLY global->reg from the
// fragment-major xfrag (1 KB coalesced per load, L2-resident), ping-pong
// buffered, NO LDS staging, NO barriers in the K-loop. Per 16-j subtile:
// 8 loads + 24 MFMA (3 acc chains, B-reuse 3). Epilogue gathers S[q[i,j], j];
// pre-softmax barrier; per-wave full-row softmax writes its P half.
__global__ __launch_bounds__(256) void attn_kernel(const float* __restrict__ x,
                                                   const int* __restrict__ q,
                                                   const float* __restrict__ R,
                                                   const unsigned short* __restrict__ xfrag,
                                                   unsigned short* __restrict__ P) {
    __shared__ float s_attn[2][BB];           // per-i logit row (8 KB)
    __shared__ unsigned short s_qs[2][BB];    // per-i q row (4 KB)

    const int tid  = threadIdx.x;
    const int w    = tid >> 6;       // 0..3
    const int lane = tid & 63;
    const int p    = w & 1;          // which i this wave serves
    const int jh   = w >> 1;         // which 512-j half
    const int lcol = lane & 15;
    const int g    = lane >> 4;
    const int lk8  = g * 8;
    const int i    = blockIdx.x * 2 + p;

    // --- q rows -> LDS (u16): 2 rows x 1024 over 256 threads, 8 each ---
    {
        const int r  = tid >> 7;
        const int c8 = (tid & 127) * 8;
        const int qi = blockIdx.x * 2 + r;
        const i32x4 qa = *reinterpret_cast<const i32x4*>(&q[qi * BB + c8]);
        const i32x4 qb = *reinterpret_cast<const i32x4*>(&q[qi * BB + c8 + 4]);
        short4_t sa, sb;
        sa[0] = (short)qa[0]; sa[1] = (short)qa[1]; sa[2] = (short)qa[2]; sa[3] = (short)qa[3];
        sb[0] = (short)qb[0]; sb[1] = (short)qb[1]; sb[2] = (short)qb[2]; sb[3] = (short)qb[3];
        *reinterpret_cast<short4_t*>(&s_qs[r][c8])     = sa;
        *reinterpret_cast<short4_t*>(&s_qs[r][c8 + 4]) = sb;
    }

    // --- A_i fragments in registers: afrag[mt*8+ks] = bf16(R[k][d]*x[i][d]) ---
    short8_t afrag[24];
    #pragma unroll
    for (int ks = 0; ks < 8; ++ks) {
        const int d0 = ks * 32 + lk8;
        const f32x4 x0 = *reinterpret_cast<const f32x4*>(&x[i * DD + d0]);
        const f32x4 x1 = *reinterpret_cast<const f32x4*>(&x[i * DD + d0 + 4]);
        #pragma unroll
        for (int mt = 0; mt < 3; ++mt) {
            const int k = mt * 16 + lcol;
            short8_t v = (short8_t)0;
            if (k < NREL) {
                const f32x4 r0 = *reinterpret_cast<const f32x4*>(&R[k * DD + d0]);
                const f32x4 r1 = *reinterpret_cast<const f32x4*>(&R[k * DD + d0 + 4]);
                #pragma unroll
                for (int e = 0; e < 4; ++e) {
                    v[e]     = (short)bf16_of(r0[e] * x0[e]);
                    v[e + 4] = (short)bf16_of(r1[e] * x1[e]);
                }
            }
            afrag[mt * 8 + ks] = v;
        }
    }

    __syncthreads();   // s_qs ready

    // Wave's B-fragment stream: subtile s covers j-group jg = jh*32 + s.
    const unsigned short* fbase = xfrag + (size_t)(jh * 32) * 4096 + lane * 8;

    short8_t ba[8], bb[8];

    auto loadb = [&](short8_t (&b)[8], int s_) {
        const unsigned short* base = fbase + (size_t)s_ * 4096;
        #pragma unroll
        for (int k = 0; k < 8; ++k)
            b[k] = *reinterpret_cast<const short8_t*>(base + k * 512);
    };
    auto computeb = [&](short8_t (&b)[8], int s_) {
        f32x4 a0 = (f32x4)0.0f, a1 = (f32x4)0.0f, a2 = (f32x4)0.0f;
        #pragma unroll
        for (int ks = 0; ks < 8; ++ks) {
            a0 = __builtin_amdgcn_mfma_f32_16x16x32_bf16(afrag[ks],      b[ks], a0, 0, 0, 0);
            a1 = __builtin_amdgcn_mfma_f32_16x16x32_bf16(afrag[8 + ks],  b[ks], a1, 0, 0, 0);
            a2 = __builtin_amdgcn_mfma_f32_16x16x32_bf16(afrag[16 + ks], b[ks], a2, 0, 0, 0);
        }
        // Exactly one lane per j holds S[q[i,j], j]: col=lcol, row=g*4+r.
        const int jl = (jh * 32 + s_) * 16 + lcol;
        const int qv = (int)s_qs[p][jl];
        if (((qv >> 2) & 3) == g) {
            const int mt = qv >> 4;                       // 0..2 (qv < 42)
            const f32x4 av = (mt == 0) ? a0 : (mt == 1) ? a1 : a2;
            const float v = (qv & 2) ? ((qv & 1) ? av[3] : av[2])
                                     : ((qv & 1) ? av[1] : av[0]);
            s_attn[p][jl] = v;
        }
    };

    loadb(ba, 0);
    for (int s = 0; s < 32; s += 2) {
        loadb(bb, (s + 1 < 32) ? s + 1 : 31);   // prefetch next subtile
        computeb(ba, s);
        loadb(ba, (s + 2 < 32) ? s + 2 : 31);   // prefetch next-next
        computeb(bb, s + 1);
    }

    __syncthreads();   // s_attn complete

    // --- softmax: full-row reduce (redundant in wave pair), write own P half ---
    f32x4 v4[4];
    #pragma unroll
    for (int kk = 0; kk < 4; ++kk)
        v4[kk] = *reinterpret_cast<const f32x4*>(&s_attn[p][kk * 256 + lane * 4]);

    float m = -1e30f;
    #pragma unroll
    for (int kk = 0; kk < 4; ++kk)
        m = fmaxf(m, fmaxf(fmaxf(v4[kk][0], v4[kk][1]), fmaxf(v4[kk][2], v4[kk][3])));
    #pragma unroll
    for (int off = 1; off < 64; off <<= 1) m = fmaxf(m, __shfl_xor(m, off));

    float e[16];
    float ssum = 0.f;
    #pragma unroll
    for (int kk = 0; kk < 4; ++kk)
        #pragma unroll
        for (int ee = 0; ee < 4; ++ee) {
            const float t2 = __expf(v4[kk][ee] - m);
            e[kk * 4 + ee] = t2;
            ssum += t2;
        }
    #pragma unroll
    for (int off = 1; off < 64; off <<= 1) ssum += __shfl_xor(ssum, off);
    const float inv = 1.0f / ssum;

    #pragma unroll
    for (int kk2 = 0; kk2 < 2; ++kk2) {
        const int kk = jh * 2 + kk2;
        short4_t pv;
        #pragma unroll
        for (int ee = 0; ee < 4; ++ee) pv[ee] = (short)bf16_of(e[kk * 4 + ee] * inv);
        *reinterpret_cast<short4_t*>(&P[i * BB + kk * 256 + lane * 4]) = pv;
    }
}

// ---------------- K3a: partial out GEMM, split-K z=4 -----------------------------
__global__ __launch_bounds__(256) void out_partial(const unsigned short* __restrict__ P,
                                                   const unsigned short* __restrict__ xbfT,
                                                   float* __restrict__ part) {
    const int tid = threadIdx.x;
    const int wave = tid >> 6, lane = tid & 63;
    const int lcol = lane & 15;
    const int lk8  = (lane >> 4) * 8;
    const int i0 = blockIdx.y * 64 + wave * 16;
    const int d0 = blockIdx.x * 64;
    const int k0 = blockIdx.z * 256;

    f32x4 acc[4];
    #pragma unroll
    for (int nt = 0; nt < 4; ++nt) acc[nt] = (f32x4)0.0f;

    #pragma unroll
    for (int ks = 0; ks < 8; ++ks) {
        const short8_t a = *reinterpret_cast<const short8_t*>(
            &P[(i0 + lcol) * BB + k0 + ks * 32 + lk8]);
        #pragma unroll
        for (int nt = 0; nt < 4; ++nt) {
            const short8_t b = *reinterpret_cast<const short8_t*>(
                &xbfT[(d0 + nt * 16 + lcol) * BB + k0 + ks * 32 + lk8]);
            acc[nt] = __builtin_amdgcn_mfma_f32_16x16x32_bf16(a, b, acc[nt], 0, 0, 0);
        }
    }

    const int rbase = (lane >> 4) * 4;
    float* pz = part + (size_t)blockIdx.z * BB * DD;
    #pragma unroll
    for (int r = 0; r < 4; ++r)
        #pragma unroll
        for (int nt = 0; nt < 4; ++nt)
            pz[(i0 + rbase + r) * DD + d0 + nt * 16 + lcol] = acc[nt][r];
}

// ---------------- K3b: out = sum_z part[z] (P already normalized) ---------------
__global__ __launch_bounds__(256) void out_reduce(const float* __restrict__ part,
                                                  float* __restrict__ out) {
    const int idx = blockIdx.x * DD + threadIdx.x;
    out[idx] = (part[idx] + part[BB * DD + idx]) +
               (part[2 * BB * DD + idx] + part[3 * BB * DD + idx]);
}

// ---------------- launch ---------------------------------------------------------
extern "C" void kernel_launch(void* const* d_in, const int* in_sizes, int n_in,
                              void* d_out, int out_size, void* d_ws, size_t ws_size,
                              hipStream_t stream) {
    (void)in_sizes; (void)n_in; (void)out_size; (void)ws_size;
    const float* x = (const float*)d_in[0];
    // d_in[1] = x_mask (unused), d_in[3] = f (unused)
    const int* q = (const int*)d_in[2];
    const float* R = (const float*)d_in[4];
    float* out = (float*)d_out;

    char* ws = (char*)d_ws;
    unsigned short* xfrag = (unsigned short*)(ws);                  // 512 KB
    unsigned short* xbfT  = (unsigned short*)(ws + (512u << 10));   // 512 KB
    unsigned short* P     = (unsigned short*)(ws + (1024u << 10));  // 2 MB
    float*          part  = (float*)(ws + (3072u << 10));           // 4 MB (z=4)

    cvt_kernel<<<dim3(16, 4), 256, 0, stream>>>(x, xfrag, xbfT);
    attn_kernel<<<dim3(512), 256, 0, stream>>>(x, q, R, xfrag, P);
    out_partial<<<dim3(4, 16, 4), 256, 0, stream>>>(P, xbfT, part);
    out_reduce<<<dim3(BB), 256, 0, stream>>>(part, out);
}